// Round 1
// baseline (292.847 us; speedup 1.0000x reference)
//
#include <hip/hip_runtime.h>

typedef __attribute__((ext_vector_type(8))) short bf16x8;
typedef __attribute__((ext_vector_type(4))) float f32x4;

#define B_N 8192
#define D_N 256
#define K_N 64

__device__ __forceinline__ unsigned short bf16_rne(float f) {
  unsigned u = __builtin_bit_cast(unsigned, f);
  u += 0x7fffu + ((u >> 16) & 1u);
  return (unsigned short)(u >> 16);
}
__device__ __forceinline__ float bf16_f32(unsigned short h) {
  return __builtin_bit_cast(float, (unsigned)h << 16);
}

// One-time f32 -> bf16 (hi) + bf16 (residual lo) split.
__global__ void convert_kernel(const float* __restrict__ src,
                               ushort* __restrict__ hi, ushort* __restrict__ lo,
                               int n4) {
  int idx = blockIdx.x * blockDim.x + threadIdx.x;
  int stride = gridDim.x * blockDim.x;
  for (int i = idx; i < n4; i += stride) {
    float4 v = ((const float4*)src)[i];
    ushort4 h, l;
    h.x = bf16_rne(v.x); l.x = bf16_rne(v.x - bf16_f32(h.x));
    h.y = bf16_rne(v.y); l.y = bf16_rne(v.y - bf16_f32(h.y));
    h.z = bf16_rne(v.z); l.z = bf16_rne(v.z - bf16_f32(h.z));
    h.w = bf16_rne(v.w); l.w = bf16_rne(v.w - bf16_f32(h.w));
    ((ushort4*)hi)[i] = h;
    ((ushort4*)lo)[i] = l;
  }
}

// xsx[b][k] = x_b^T Sigma_k x_b via fused GEMM (Y' = X @ Sigma_k^T, contraction
// over e = Sigma's 2nd index) + row-dot epilogue with exact f32 X.
// 3-term bf16 split: Xh*Sh + Xl*Sh + Xh*Sl (f32 accum).
// MODE 0: read pre-converted bf16 from ws.  MODE 1: convert f32 in-block.
template <int MODE>
__global__ __launch_bounds__(512, 2) void xsx_kernel(
    const float* __restrict__ X, const float* __restrict__ Sigma,
    const ushort* __restrict__ Xh, const ushort* __restrict__ Xl,
    const ushort* __restrict__ Sh, const ushort* __restrict__ Sl,
    float* __restrict__ xsx) {
  constexpr int BM = 128, KT = 32;
  __shared__ __align__(16) ushort Ah[BM][KT];   //  8 KB  X hi  [b_loc][e]
  __shared__ __align__(16) ushort Al[BM][KT];   //  8 KB  X lo
  __shared__ __align__(16) ushort Bh[D_N][KT];  // 16 KB  Sigma hi [d][e]
  __shared__ __align__(16) ushort Bl[D_N][KT];  // 16 KB  Sigma lo
  __shared__ float red[4][BM];                  //  2 KB  cross-wave d-reduction

  const int tid = threadIdx.x;
  const int lane = tid & 63;
  const int wid = tid >> 6;  // 0..7
  const int wm = wid >> 2;   // 0..1 : row half
  const int wn = wid & 3;    // 0..3 : d quarter
  const int lr = lane & 15;
  const int lk = lane >> 4;

  const int b0 = blockIdx.x * BM;
  const int kk = blockIdx.y;
  const size_t soff = (size_t)kk * D_N * D_N;

  f32x4 acc[4][4];
#pragma unroll
  for (int mi = 0; mi < 4; ++mi)
#pragma unroll
    for (int ni = 0; ni < 4; ++ni) acc[mi][ni] = (f32x4){0.f, 0.f, 0.f, 0.f};

  for (int ec = 0; ec < D_N / KT; ++ec) {
    const int e0 = ec * KT;
    __syncthreads();
    if (MODE == 0) {
      {  // A tiles: 128 rows x 32 cols bf16 (hi+lo) = 512 x 16B each
        const int row = tid >> 2, c8 = (tid & 3) * 8;
        *(uint4*)&Ah[row][c8] = *(const uint4*)(Xh + (size_t)(b0 + row) * D_N + e0 + c8);
        *(uint4*)&Al[row][c8] = *(const uint4*)(Xl + (size_t)(b0 + row) * D_N + e0 + c8);
      }
#pragma unroll
      for (int r = 0; r < 2; ++r) {  // B tiles: 256 rows x 32 cols
        const int i = tid + 512 * r;
        const int d = i >> 2, c8 = (i & 3) * 8;
        *(uint4*)&Bh[d][c8] = *(const uint4*)(Sh + soff + (size_t)d * D_N + e0 + c8);
        *(uint4*)&Bl[d][c8] = *(const uint4*)(Sl + soff + (size_t)d * D_N + e0 + c8);
      }
    } else {
#pragma unroll
      for (int r = 0; r < 2; ++r) {
        const int i = tid + 512 * r;
        const int row = i >> 3, c4 = (i & 7) * 4;
        const float4 v = *(const float4*)(X + (size_t)(b0 + row) * D_N + e0 + c4);
        ushort4 h, l;
        h.x = bf16_rne(v.x); l.x = bf16_rne(v.x - bf16_f32(h.x));
        h.y = bf16_rne(v.y); l.y = bf16_rne(v.y - bf16_f32(h.y));
        h.z = bf16_rne(v.z); l.z = bf16_rne(v.z - bf16_f32(h.z));
        h.w = bf16_rne(v.w); l.w = bf16_rne(v.w - bf16_f32(h.w));
        *(ushort4*)&Ah[row][c4] = h;
        *(ushort4*)&Al[row][c4] = l;
      }
#pragma unroll
      for (int r = 0; r < 4; ++r) {
        const int i = tid + 512 * r;
        const int d = i >> 3, c4 = (i & 7) * 4;
        const float4 v = *(const float4*)(Sigma + soff + (size_t)d * D_N + e0 + c4);
        ushort4 h, l;
        h.x = bf16_rne(v.x); l.x = bf16_rne(v.x - bf16_f32(h.x));
        h.y = bf16_rne(v.y); l.y = bf16_rne(v.y - bf16_f32(h.y));
        h.z = bf16_rne(v.z); l.z = bf16_rne(v.z - bf16_f32(h.z));
        h.w = bf16_rne(v.w); l.w = bf16_rne(v.w - bf16_f32(h.w));
        *(ushort4*)&Bh[d][c4] = h;
        *(ushort4*)&Bl[d][c4] = l;
      }
    }
    __syncthreads();

    bf16x8 ah[4], al[4];
#pragma unroll
    for (int mi = 0; mi < 4; ++mi) {
      ah[mi] = *(const bf16x8*)&Ah[wm * 64 + mi * 16 + lr][lk * 8];
      al[mi] = *(const bf16x8*)&Al[wm * 64 + mi * 16 + lr][lk * 8];
    }
#pragma unroll
    for (int ni = 0; ni < 4; ++ni) {
      const bf16x8 bh = *(const bf16x8*)&Bh[wn * 64 + ni * 16 + lr][lk * 8];
      const bf16x8 bl = *(const bf16x8*)&Bl[wn * 64 + ni * 16 + lr][lk * 8];
#pragma unroll
      for (int mi = 0; mi < 4; ++mi) {
        acc[mi][ni] = __builtin_amdgcn_mfma_f32_16x16x32_bf16(ah[mi], bh, acc[mi][ni], 0, 0, 0);
        acc[mi][ni] = __builtin_amdgcn_mfma_f32_16x16x32_bf16(al[mi], bh, acc[mi][ni], 0, 0, 0);
        acc[mi][ni] = __builtin_amdgcn_mfma_f32_16x16x32_bf16(ah[mi], bl, acc[mi][ni], 0, 0, 0);
      }
    }
  }

  // Epilogue: p[b] += Y'[b][d] * X[b][d] over the wave's 64 d-columns.
  // C/D layout (m89-verified): col = lane&15, row = (lane>>4)*4 + j.
  float p[4][4];
#pragma unroll
  for (int mi = 0; mi < 4; ++mi)
#pragma unroll
    for (int j = 0; j < 4; ++j) p[mi][j] = 0.f;

#pragma unroll
  for (int mi = 0; mi < 4; ++mi) {
#pragma unroll
    for (int j = 0; j < 4; ++j) {
      const int brow = b0 + wm * 64 + mi * 16 + lk * 4 + j;
      const float* xr = X + (size_t)brow * D_N + wn * 64 + lr;
#pragma unroll
      for (int ni = 0; ni < 4; ++ni)
        p[mi][j] = fmaf(acc[mi][ni][j], xr[ni * 16], p[mi][j]);
    }
  }
#pragma unroll
  for (int mi = 0; mi < 4; ++mi)
#pragma unroll
    for (int j = 0; j < 4; ++j) {
      float v = p[mi][j];
      v += __shfl_xor(v, 1);
      v += __shfl_xor(v, 2);
      v += __shfl_xor(v, 4);
      v += __shfl_xor(v, 8);
      p[mi][j] = v;
    }
  if (lr == 0) {
#pragma unroll
    for (int mi = 0; mi < 4; ++mi)
#pragma unroll
      for (int j = 0; j < 4; ++j)
        red[wn][wm * 64 + mi * 16 + lk * 4 + j] = p[mi][j];
  }
  __syncthreads();
  if (tid < BM) {
    const float s = red[0][tid] + red[1][tid] + red[2][tid] + red[3][tid];
    xsx[(size_t)(b0 + tid) * K_N + kk] = s;
  }
}

// One wave per batch row b; lane k owns class k in [0,64).
__global__ __launch_bounds__(256) void loss_kernel(
    const float* __restrict__ X, const int* __restrict__ y,
    const float* __restrict__ mu, const int* __restrict__ loss_type,
    const float* __restrict__ xsx, float* __restrict__ out) {
  __shared__ float mu_s[D_N * K_N];  // 64 KB
  __shared__ float x_s[4][D_N];      //  4 KB
  const int tid = threadIdx.x;
  const int wid = tid >> 6;
  const int lane = tid & 63;
  const int b = blockIdx.x * 4 + wid;

  for (int i = tid; i < D_N * K_N / 4; i += 256)
    ((float4*)mu_s)[i] = ((const float4*)mu)[i];
  ((float4*)&x_s[wid][0])[lane] = ((const float4*)(X + (size_t)b * D_N))[lane];
  __syncthreads();

  const int yb = y[b];
  const int lt = loss_type[0];

  float logit = 0.f;
#pragma unroll 8
  for (int d = 0; d < D_N; ++d)
    logit = fmaf(x_s[wid][d], mu_s[d * K_N + lane], logit);

  float term;
  if (lt == 1) {
    const float xv = xsx[(size_t)b * K_N + lane];
    const float psi = sqrtf(fmaxf(xv + logit * logit, 0.f));
    const float bk = (lane <= yb) ? 1.f : 0.f;
    const float kap = ((lane == yb) ? 1.f : 0.f) - 0.5f * bk;
    // psi/2 - softplus(psi) = -psi/2 - log1p(exp(-psi)) for psi >= 0
    term = logit * kap + bk * (-0.5f * psi - log1pf(expf(-psi)));
  } else {
    const float sp = (logit > 0.f) ? (logit + log1pf(expf(-logit)))
                                   : log1pf(expf(logit));
    term = ((lane == yb) ? logit : 0.f) - ((lane <= yb) ? sp : 0.f);
  }
#pragma unroll
  for (int s = 1; s < 64; s <<= 1) term += __shfl_xor(term, s);
  if (lane == 0) out[b] = -term;
}

extern "C" void kernel_launch(void* const* d_in, const int* in_sizes, int n_in,
                              void* d_out, int out_size, void* d_ws, size_t ws_size,
                              hipStream_t stream) {
  const float* X = (const float*)d_in[0];
  const int* y = (const int*)d_in[1];
  const float* mu = (const float*)d_in[2];
  const float* Sigma = (const float*)d_in[3];
  const int* lt = (const int*)d_in[4];
  float* out = (float*)d_out;

  const size_t XN = (size_t)B_N * D_N;        // 2,097,152 elems
  const size_t SN = (size_t)K_N * D_N * D_N;  // 4,194,304 elems
  const size_t xh_off = 0;
  const size_t xl_off = xh_off + XN * 2;
  const size_t sh_off = xl_off + XN * 2;
  const size_t sl_off = sh_off + SN * 2;
  const size_t xsx_off = sl_off + SN * 2;
  const size_t need = xsx_off + (size_t)B_N * K_N * 4;  // ~27.3 MB

  char* w = (char*)d_ws;
  if (ws_size >= need) {
    ushort* Xh = (ushort*)(w + xh_off);
    ushort* Xl = (ushort*)(w + xl_off);
    ushort* Sh = (ushort*)(w + sh_off);
    ushort* Sl = (ushort*)(w + sl_off);
    float* xsx = (float*)(w + xsx_off);
    hipLaunchKernelGGL(convert_kernel, dim3(1024), dim3(256), 0, stream,
                       X, Xh, Xl, (int)(XN / 4));
    hipLaunchKernelGGL(convert_kernel, dim3(2048), dim3(256), 0, stream,
                       Sigma, Sh, Sl, (int)(SN / 4));
    hipLaunchKernelGGL((xsx_kernel<0>), dim3(B_N / 128, K_N), dim3(512), 0, stream,
                       X, Sigma, Xh, Xl, Sh, Sl, xsx);
    hipLaunchKernelGGL(loss_kernel, dim3(B_N / 4), dim3(256), 0, stream,
                       X, y, mu, lt, xsx, out);
  } else {
    float* xsx = (float*)w;  // needs 2 MB
    hipLaunchKernelGGL((xsx_kernel<1>), dim3(B_N / 128, K_N), dim3(512), 0, stream,
                       X, Sigma, (const ushort*)nullptr, (const ushort*)nullptr,
                       (const ushort*)nullptr, (const ushort*)nullptr, xsx);
    hipLaunchKernelGGL(loss_kernel, dim3(B_N / 4), dim3(256), 0, stream,
                       X, y, mu, lt, xsx, out);
  }
}